// Round 10
// baseline (1511.192 us; speedup 1.0000x reference)
//
#include <hip/hip_runtime.h>

static constexpr int TT = 512;   // sequence length
static constexpr int BB = 256;   // batch

// LDS-only barrier: no vmcnt(0) drain, so global loads stay in flight across
// it (T4/T14 pattern). lgkmcnt(0) makes prior LDS writes visible.
#define BARRIER() do { \
    asm volatile("s_waitcnt lgkmcnt(0)" ::: "memory"); \
    __builtin_amdgcn_s_barrier(); \
    asm volatile("" ::: "memory"); \
  } while (0)

__device__ __forceinline__ float sigmoid_fast(float v) {
  const float e = __builtin_amdgcn_exp2f(v * -1.44269504088896340736f);
  return __builtin_amdgcn_rcpf(1.0f + e);
}
__device__ __forceinline__ float dpp_add_xor1(float v) {
  const int p = __builtin_amdgcn_update_dpp(0, __builtin_bit_cast(int, v),
                                            0xB1, 0xF, 0xF, true);
  return v + __builtin_bit_cast(float, p);
}
__device__ __forceinline__ float dpp_add_xor2(float v) {
  const int p = __builtin_amdgcn_update_dpp(0, __builtin_bit_cast(int, v),
                                            0x4E, 0xF, 0xF, true);
  return v + __builtin_bit_cast(float, p);
}
__device__ __forceinline__ float swz_add_xor4(float v) {
  const int p = __builtin_amdgcn_ds_swizzle(__builtin_bit_cast(int, v), 0x101F);
  return v + __builtin_bit_cast(float, p);
}
// padded LDS offset: +4 words per 32 -> 32-float slice bases spread over banks
__device__ __forceinline__ constexpr int pofs(int k) { return k + ((k >> 5) << 2); }

// 128-FMA 4-gate dot over 8 float4 (SL=32), weights w[128]
#define DOT128(XV, W, AI, AF, AG, AO)                                        \
  _Pragma("unroll")                                                          \
  for (int jj = 0; jj < 8; ++jj) {                                           \
    const float4 v = (XV)[jj];                                               \
    const float* wj = &(W)[16 * jj];                                         \
    AI = fmaf(v.x, wj[0],  AI);  AF = fmaf(v.x, wj[1],  AF);                 \
    AG = fmaf(v.x, wj[2],  AG);  AO = fmaf(v.x, wj[3],  AO);                 \
    AI = fmaf(v.y, wj[4],  AI);  AF = fmaf(v.y, wj[5],  AF);                 \
    AG = fmaf(v.y, wj[6],  AG);  AO = fmaf(v.y, wj[7],  AO);                 \
    AI = fmaf(v.z, wj[8],  AI);  AF = fmaf(v.z, wj[9],  AF);                 \
    AG = fmaf(v.z, wj[10], AG);  AO = fmaf(v.z, wj[11], AO);                 \
    AI = fmaf(v.w, wj[12], AI);  AF = fmaf(v.w, wj[13], AF);                 \
    AG = fmaf(v.w, wj[14], AG);  AO = fmaf(v.w, wj[15], AO);                 \
  }

// 32-FMA 4-gate dot over 2 float4 (SL=8), weights w[32]
#define DOT32(XV, W, AI, AF, AG, AO)                                         \
  _Pragma("unroll")                                                          \
  for (int jj = 0; jj < 2; ++jj) {                                           \
    const float4 v = (XV)[jj];                                               \
    const float* wj = &(W)[16 * jj];                                         \
    AI = fmaf(v.x, wj[0],  AI);  AF = fmaf(v.x, wj[1],  AF);                 \
    AG = fmaf(v.x, wj[2],  AG);  AO = fmaf(v.x, wj[3],  AO);                 \
    AI = fmaf(v.y, wj[4],  AI);  AF = fmaf(v.y, wj[5],  AF);                 \
    AG = fmaf(v.y, wj[6],  AG);  AO = fmaf(v.y, wj[7],  AO);                 \
    AI = fmaf(v.z, wj[8],  AI);  AF = fmaf(v.z, wj[9],  AF);                 \
    AG = fmaf(v.z, wj[10], AG);  AO = fmaf(v.z, wj[11], AO);                 \
    AI = fmaf(v.w, wj[12], AI);  AF = fmaf(v.w, wj[13], AF);                 \
    AG = fmaf(v.w, wj[14], AG);  AO = fmaf(v.w, wj[15], AO);                 \
  }

// ===================== r4-proven LSTM layer (enc1, enc2) ===================
template<int DIN, int H, int NSu, bool WRITE_SEQ, bool WRITE_LAST>
__global__ void __launch_bounds__(512, 2)
lstm_unit(const float* __restrict__ xin, const float* __restrict__ Wk,
          const float* __restrict__ Wr, const float* __restrict__ bias,
          float* __restrict__ seq_out, float* __restrict__ last_out)
{
  constexpr int NTH  = 512;
  static_assert(H * NSu == NTH, "block = H*NSu = 512");
  constexpr int KTOT = DIN + H;
  constexpr int SL   = KTOT / NSu;
  constexpr int C4H  = 4 * H;
  constexpr int XH   = DIN + H;
  constexpr int UPW  = 64 / NSu;
  static_assert(SL * NSu == KTOT && (SL % 4) == 0, "slice float4-able");
  static_assert(NSu == 4 || NSu == 8, "butterfly depth");

  const int tid = (int)threadIdx.x;
  const int b   = (int)blockIdx.x;
  const int l   = tid & 63;
  const int wv  = tid >> 6;
  const int sl  = l & (NSu - 1);
  const int u   = wv * UPW + (l / NSu);

  __shared__ __align__(16) float xh0[XH], xh1[XH];

  float w[SL * 4];
  #pragma unroll
  for (int i = 0; i < SL; ++i) {
    const int k = sl * SL + i;
    const float* col = (k < DIN) ? &Wk[(size_t)k * C4H] : &Wr[(size_t)(k - DIN) * C4H];
    #pragma unroll
    for (int g = 0; g < 4; ++g) w[i * 4 + g] = col[g * H + u];
  }
  const float bi_ = bias[u], bf_ = bias[H + u], bg_ = bias[2 * H + u], bo_ = bias[3 * H + u];

  if (tid < H) xh0[DIN + tid] = 0.f;
  if (tid < DIN / 4)
    *((float4*)xh0 + tid) = *(const float4*)&xin[(size_t)b * TT * DIN + 4 * tid];
  BARRIER();

  float cst = 0.f;
  for (int t = 0; t < TT; ++t) {
    float* xc = (t & 1) ? xh1 : xh0;
    float* xn = (t & 1) ? xh0 : xh1;

    float4 xr;
    const bool do_stage = (tid < DIN / 4) && (t + 1 < TT);
    if (do_stage) xr = *(const float4*)&xin[((size_t)b * TT + (t + 1)) * DIN + 4 * tid];

    const float4* xv = (const float4*)(xc + sl * SL);
    float ai = 0.f, af = 0.f, ag = 0.f, ao = 0.f;
    #pragma unroll
    for (int j = 0; j < SL / 4; ++j) {
      const float4 v = xv[j];
      const float* wj = &w[16 * j];
      ai = fmaf(v.x, wj[0],  ai);  af = fmaf(v.x, wj[1],  af);
      ag = fmaf(v.x, wj[2],  ag);  ao = fmaf(v.x, wj[3],  ao);
      ai = fmaf(v.y, wj[4],  ai);  af = fmaf(v.y, wj[5],  af);
      ag = fmaf(v.y, wj[6],  ag);  ao = fmaf(v.y, wj[7],  ao);
      ai = fmaf(v.z, wj[8],  ai);  af = fmaf(v.z, wj[9],  af);
      ag = fmaf(v.z, wj[10], ag);  ao = fmaf(v.z, wj[11], ao);
      ai = fmaf(v.w, wj[12], ai);  af = fmaf(v.w, wj[13], af);
      ag = fmaf(v.w, wj[14], ag);  ao = fmaf(v.w, wj[15], ao);
    }
    ai = dpp_add_xor1(ai); af = dpp_add_xor1(af);
    ag = dpp_add_xor1(ag); ao = dpp_add_xor1(ao);
    ai = dpp_add_xor2(ai); af = dpp_add_xor2(af);
    ag = dpp_add_xor2(ag); ao = dpp_add_xor2(ao);
    if constexpr (NSu == 8) {
      ai = swz_add_xor4(ai); af = swz_add_xor4(af);
      ag = swz_add_xor4(ag); ao = swz_add_xor4(ao);
    }
    const float gi = sigmoid_fast(ai + bi_);
    const float gf = sigmoid_fast(af + bf_);
    const float go = sigmoid_fast(ao + bo_);
    const float gg = fmaxf(ag + bg_, 0.f);
    cst = fmaf(gf, cst, gi * gg);
    const float h = go * fmaxf(cst, 0.f);
    if (sl == 0) {
      xn[DIN + u] = h;
      if constexpr (WRITE_SEQ)  seq_out[((size_t)b * TT + t) * H + u] = h;
      if constexpr (WRITE_LAST) { if (t == TT - 1) last_out[(size_t)b * H + u] = h; }
    }
    if (do_stage) *((float4*)xn + tid) = xr;
    if (t < TT - 1) BARRIER();
  }
}

// ===========================================================================
// dec_fused = r6 winner (~537 us) + 3 targeted fixes (r9, bug-fixed):
//  (1) hb2d padded (pofs)       -> removes 4-way conflict on LSTM4 DOT reads
//  (2) zx3 rows padded, group stride 132 -> removes 4-way conflict on zq
//      reads. ROW SIZE 528 (max index 3*132+127 = 523; r9's 516 overflowed)
//  (3) dense partial via readlane of register hprev -> -4 ds_read_b128/thr
// r6's COALESCED gemm3 layout (c3 = tid) kept verbatim (r7 lesson).
// ===========================================================================
__global__ void __launch_bounds__(512, 2)
dec_fused(const float* __restrict__ zrow,  // [B,64]
          const float* __restrict__ Wd1k,  // [64,256]
          const float* __restrict__ Wd1r,  // [64,256]
          const float* __restrict__ bd1,   // [256]
          const float* __restrict__ Wd2k,  // [64,512]
          const float* __restrict__ Wd2r,  // [128,512]
          const float* __restrict__ bd2,   // [512]
          const float* __restrict__ Wout,  // [128,64]
          const float* __restrict__ boutp, // [64]
          float* __restrict__ out)         // [B,T,64]
{
  const int tid = (int)threadIdx.x, b = (int)blockIdx.x;
  const int l  = tid & 63, wv = tid >> 6;
  const int sl1 = l & 3,  u1 = wv * 16 + (l >> 2);   // LSTM4: NSu=4, H=128
  const int sl2 = l & 7,  u2 = wv * 8  + (l >> 3);   // LSTM3: NSu=8, H=64
  const int c3 = tid;                                 // gemm3 column (512)

  __shared__ __align__(16) float zx3[2][8][528];      // padded: grp g @ 132g
  __shared__ __align__(16) float hd1c[2][8][64];      // d1 h chunks
  __shared__ __align__(16) float hb2d[2][144];        // LSTM4 h, padded
  __shared__ __align__(16) float dp[2][512];          // dense partials
  __shared__ __align__(16) float zl[64];

  float w[32];                                        // Wd1r slice
  #pragma unroll
  for (int i = 0; i < 8; ++i) {
    const float* col = Wd1r + (size_t)(sl2 * 8 + i) * 256;
    #pragma unroll
    for (int g = 0; g < 4; ++g) w[i * 4 + g] = col[g * 64 + u2];
  }
  float w1[128];                                      // Wd2r slice
  #pragma unroll
  for (int i = 0; i < 32; ++i) {
    const float* col = Wd2r + (size_t)(sl1 * 32 + i) * 512;
    #pragma unroll
    for (int g = 0; g < 4; ++g) w1[i * 4 + g] = col[g * 128 + u1];
  }
  float wout_r[16];
  #pragma unroll
  for (int jj = 0; jj < 16; ++jj) wout_r[jj] = Wout[(size_t)(16 * wv + jj) * 64 + l];
  const float boutr = boutp[l];
  const float bd2c = bd2[c3];

  if (tid < 16) ((float4*)zl)[tid] = ((const float4*)(zrow + (size_t)b * 64))[tid];
  if (tid < 64)  hd1c[1][7][tid] = 0.f;
  if (tid < 128) hb2d[1][pofs(tid)] = 0.f;
  float zxa3[8];
  #pragma unroll
  for (int r = 0; r < 8; ++r) zxa3[r] = bd2c;
  BARRIER();

  // fold z@Wd1k once (per-lane slice partials; bd1 seeded at lane sl2==0)
  float zi = (sl2 == 0) ? bd1[u2]       : 0.f;
  float zf = (sl2 == 0) ? bd1[64 + u2]  : 0.f;
  float zg = (sl2 == 0) ? bd1[128 + u2] : 0.f;
  float zo = (sl2 == 0) ? bd1[192 + u2] : 0.f;
  #pragma unroll
  for (int i = 0; i < 8; ++i) {
    const int k = sl2 * 8 + i;
    const float zv = zl[k];
    const float* col = Wd1k + (size_t)k * 256;
    zi = fmaf(zv, col[u2],       zi);
    zf = fmaf(zv, col[64 + u2],  zf);
    zg = fmaf(zv, col[128 + u2], zg);
    zo = fmaf(zv, col[192 + u2], zo);
  }

  float cst1 = 0.f, cst2 = 0.f;
  float hprev = 0.f;                                  // h4(s-1), register copy

  for (int t = -8; t < 530; ++t) {
    const int j = t & 7;
    const int ch = t >> 3;
    const bool rd1 = (t >= 0 && t < TT);
    const bool g3  = (t >= 8 && t < 520);             // build chunk ch-1
    const int  s   = t - 16;
    const bool rd2 = (s >= 0 && s < TT);

    float wk3r[8];                                    // coalesced (c3 = tid)
    if (g3) {
      #pragma unroll
      for (int i = 0; i < 8; ++i)
        wk3r[i] = Wd2k[(size_t)(8 * j + i) * 512 + c3];
    }

    // ---- LSTM3 step t (const-z input folded in zi..zo) ----
    if (rd1) {
      const int row = t & 7, buf = ch & 1;
      const int prow = (t - 1) & 7, pbuf = ((t - 1) >> 3) & 1;
      const float4* xv = (const float4*)&hd1c[pbuf][prow][sl2 * 8];
      float ai = zi, af = zf, ag = zg, ao = zo;
      DOT32(xv, w, ai, af, ag, ao);
      ai = dpp_add_xor1(ai); af = dpp_add_xor1(af);
      ag = dpp_add_xor1(ag); ao = dpp_add_xor1(ao);
      ai = dpp_add_xor2(ai); af = dpp_add_xor2(af);
      ag = dpp_add_xor2(ag); ao = dpp_add_xor2(ao);
      ai = swz_add_xor4(ai); af = swz_add_xor4(af);
      ag = swz_add_xor4(ag); ao = swz_add_xor4(ao);
      const float gi = sigmoid_fast(ai);
      const float gf = sigmoid_fast(af);
      const float go = sigmoid_fast(ao);
      const float gg_ = fmaxf(ag, 0.f);
      cst1 = fmaf(gf, cst1, gi * gg_);
      const float h = go * fmaxf(cst1, 0.f);
      if (sl2 == 0) hd1c[buf][row][u2] = h;
    }

    // ---- dense partial of h4(s-1) via readlane (no LDS h reads) ----
    if (s >= 1 && s <= TT) {
      float a = 0.f;
      #pragma unroll
      for (int q = 0; q < 16; ++q) {
        const int hq_i = __builtin_amdgcn_readlane(__builtin_bit_cast(int, hprev), 4 * q);
        a = fmaf(__builtin_bit_cast(float, hq_i), wout_r[q], a);
      }
      dp[(s - 1) & 1][wv * 64 + l] = a;
    }
    // ---- dense reduce of h4(s-2) (dp sealed by the previous barrier) ----
    if (s >= 2 && s <= TT + 1 && wv == 7) {
      const float* dq = dp[s & 1];
      float o = boutr;
      #pragma unroll
      for (int q = 0; q < 8; ++q) o += dq[q * 64 + l];
      out[((size_t)b * TT + (s - 2)) * 64 + l] = o;
    }

    // ---- LSTM4 step s (16 behind) ----
    if (rd2) {
      const int row2 = s & 7, buf2 = (s >> 3) & 1;
      const float4* xv2 = (const float4*)&hb2d[(s + 1) & 1][sl1 * 36];  // padded
      const float zq = zx3[buf2][row2][sl1 * 132 + u1];                 // padded
      float ai = (sl1 == 0) ? zq : 0.f;
      float af = (sl1 == 1) ? zq : 0.f;
      float ag = (sl1 == 2) ? zq : 0.f;
      float ao = (sl1 == 3) ? zq : 0.f;
      DOT128(xv2, w1, ai, af, ag, ao);
      ai = dpp_add_xor1(ai); af = dpp_add_xor1(af);
      ag = dpp_add_xor1(ag); ao = dpp_add_xor1(ao);
      ai = dpp_add_xor2(ai); af = dpp_add_xor2(af);
      ag = dpp_add_xor2(ag); ao = dpp_add_xor2(ao);
      const float gi = sigmoid_fast(ai);
      const float gf = sigmoid_fast(af);
      const float go = sigmoid_fast(ao);
      const float gg_ = fmaxf(ag, 0.f);
      cst2 = fmaf(gf, cst2, gi * gg_);
      const float h2 = go * fmaxf(cst2, 0.f);
      hprev = h2;                                     // all lanes (redundant)
      if (sl1 == 0) hb2d[s & 1][pofs(u1)] = h2;
    }

    // ---- gemm3: zx3 chunk ch-1 from hd1c (r6 verbatim, padded write) ----
    if (g3) {
      const int cc = ch - 1;
      #pragma unroll
      for (int r = 0; r < 8; ++r) {
        const float4 ha  = *(const float4*)&hd1c[cc & 1][r][8 * j];
        const float4 hbq = *(const float4*)&hd1c[cc & 1][r][8 * j + 4];
        float a = zxa3[r];
        a = fmaf(ha.x,  wk3r[0], a);  a = fmaf(ha.y,  wk3r[1], a);
        a = fmaf(ha.z,  wk3r[2], a);  a = fmaf(ha.w,  wk3r[3], a);
        a = fmaf(hbq.x, wk3r[4], a);  a = fmaf(hbq.y, wk3r[5], a);
        a = fmaf(hbq.z, wk3r[6], a);  a = fmaf(hbq.w, wk3r[7], a);
        zxa3[r] = a;
      }
      if (j == 7) {
        #pragma unroll
        for (int r = 0; r < 8; ++r) {
          zx3[cc & 1][r][tid + (tid >> 7) * 4] = zxa3[r];   // grp stride 132
          zxa3[r] = bd2c;
        }
      }
    }

    if (t < 529) BARRIER();
  }
}

extern "C" void kernel_launch(void* const* d_in, const int* in_sizes, int n_in,
                              void* d_out, int out_size, void* d_ws, size_t ws_size,
                              hipStream_t stream) {
  const float* x    = (const float*)d_in[0];
  const float* Wk1  = (const float*)d_in[1];
  const float* Wr1  = (const float*)d_in[2];
  const float* b1   = (const float*)d_in[3];
  const float* Wk2  = (const float*)d_in[4];
  const float* Wr2  = (const float*)d_in[5];
  const float* b2   = (const float*)d_in[6];
  const float* Wd1k = (const float*)d_in[7];
  const float* Wd1r = (const float*)d_in[8];
  const float* bd1  = (const float*)d_in[9];
  const float* Wd2k = (const float*)d_in[10];
  const float* Wd2r = (const float*)d_in[11];
  const float* bd2  = (const float*)d_in[12];
  const float* Wout = (const float*)d_in[13];
  const float* bout = (const float*)d_in[14];
  float* out = (float*)d_out;

  // ws: h1 [B,T,128] (64 MB) + z [B,64] — proven available since r4
  const size_t h1_elems = (size_t)BB * TT * 128;
  if (ws_size < (h1_elems + (size_t)BB * 64) * sizeof(float)) return;
  float* h1 = (float*)d_ws;
  float* z  = h1 + h1_elems;

  // encoder 1: 64 -> 128, seq out (r4-proven, 575 us)
  lstm_unit<64, 128, 4, true,  false><<<BB, 512, 0, stream>>>(x,  Wk1, Wr1, b1, h1, nullptr);
  // encoder 2: 128 -> 64, last state only (r4-proven, ~145 us)
  lstm_unit<128, 64, 8, false, true ><<<BB, 512, 0, stream>>>(h1, Wk2, Wr2, b2, nullptr, z);
  // decoder fused: dec1 + dec2 + TimeDistributed Dense (r6 winner + fixes)
  dec_fused<<<BB, 512, 0, stream>>>(z, Wd1k, Wd1r, bd1, Wd2k, Wd2r, bd2,
                                    Wout, bout, out);
}

// Round 11
// 1472.255 us; speedup vs baseline: 1.0264x; 1.0264x over previous
//
#include <hip/hip_runtime.h>

static constexpr int TT = 512;   // sequence length
static constexpr int BB = 256;   // batch

// LDS-only barrier: no vmcnt(0) drain, so global loads stay in flight across
// it (T4/T14 pattern). lgkmcnt(0) makes prior LDS writes visible.
#define BARRIER() do { \
    asm volatile("s_waitcnt lgkmcnt(0)" ::: "memory"); \
    __builtin_amdgcn_s_barrier(); \
    asm volatile("" ::: "memory"); \
  } while (0)

__device__ __forceinline__ float sigmoid_fast(float v) {
  const float e = __builtin_amdgcn_exp2f(v * -1.44269504088896340736f);
  return __builtin_amdgcn_rcpf(1.0f + e);
}
__device__ __forceinline__ float dpp_add_xor1(float v) {
  const int p = __builtin_amdgcn_update_dpp(0, __builtin_bit_cast(int, v),
                                            0xB1, 0xF, 0xF, true);
  return v + __builtin_bit_cast(float, p);
}
__device__ __forceinline__ float dpp_add_xor2(float v) {
  const int p = __builtin_amdgcn_update_dpp(0, __builtin_bit_cast(int, v),
                                            0x4E, 0xF, 0xF, true);
  return v + __builtin_bit_cast(float, p);
}
__device__ __forceinline__ float swz_add_xor4(float v) {
  const int p = __builtin_amdgcn_ds_swizzle(__builtin_bit_cast(int, v), 0x101F);
  return v + __builtin_bit_cast(float, p);
}

// 128-FMA 4-gate dot over 8 float4 (SL=32), weights w[128]
#define DOT128(XV, W, AI, AF, AG, AO)                                        \
  _Pragma("unroll")                                                          \
  for (int jj = 0; jj < 8; ++jj) {                                           \
    const float4 v = (XV)[jj];                                               \
    const float* wj = &(W)[16 * jj];                                         \
    AI = fmaf(v.x, wj[0],  AI);  AF = fmaf(v.x, wj[1],  AF);                 \
    AG = fmaf(v.x, wj[2],  AG);  AO = fmaf(v.x, wj[3],  AO);                 \
    AI = fmaf(v.y, wj[4],  AI);  AF = fmaf(v.y, wj[5],  AF);                 \
    AG = fmaf(v.y, wj[6],  AG);  AO = fmaf(v.y, wj[7],  AO);                 \
    AI = fmaf(v.z, wj[8],  AI);  AF = fmaf(v.z, wj[9],  AF);                 \
    AG = fmaf(v.z, wj[10], AG);  AO = fmaf(v.z, wj[11], AO);                 \
    AI = fmaf(v.w, wj[12], AI);  AF = fmaf(v.w, wj[13], AF);                 \
    AG = fmaf(v.w, wj[14], AG);  AO = fmaf(v.w, wj[15], AO);                 \
  }

// 32-FMA 4-gate dot over 2 float4 (SL=8), weights w[32]
#define DOT32(XV, W, AI, AF, AG, AO)                                         \
  _Pragma("unroll")                                                          \
  for (int jj = 0; jj < 2; ++jj) {                                           \
    const float4 v = (XV)[jj];                                               \
    const float* wj = &(W)[16 * jj];                                         \
    AI = fmaf(v.x, wj[0],  AI);  AF = fmaf(v.x, wj[1],  AF);                 \
    AG = fmaf(v.x, wj[2],  AG);  AO = fmaf(v.x, wj[3],  AO);                 \
    AI = fmaf(v.y, wj[4],  AI);  AF = fmaf(v.y, wj[5],  AF);                 \
    AG = fmaf(v.y, wj[6],  AG);  AO = fmaf(v.y, wj[7],  AO);                 \
    AI = fmaf(v.z, wj[8],  AI);  AF = fmaf(v.z, wj[9],  AF);                 \
    AG = fmaf(v.z, wj[10], AG);  AO = fmaf(v.z, wj[11], AO);                 \
    AI = fmaf(v.w, wj[12], AI);  AF = fmaf(v.w, wj[13], AF);                 \
    AG = fmaf(v.w, wj[14], AG);  AO = fmaf(v.w, wj[15], AO);                 \
  }

// ===================== r4-proven LSTM layer (enc1, enc2) ===================
template<int DIN, int H, int NSu, bool WRITE_SEQ, bool WRITE_LAST>
__global__ void __launch_bounds__(512, 2)
lstm_unit(const float* __restrict__ xin, const float* __restrict__ Wk,
          const float* __restrict__ Wr, const float* __restrict__ bias,
          float* __restrict__ seq_out, float* __restrict__ last_out)
{
  constexpr int NTH  = 512;
  static_assert(H * NSu == NTH, "block = H*NSu = 512");
  constexpr int KTOT = DIN + H;
  constexpr int SL   = KTOT / NSu;
  constexpr int C4H  = 4 * H;
  constexpr int XH   = DIN + H;
  constexpr int UPW  = 64 / NSu;
  static_assert(SL * NSu == KTOT && (SL % 4) == 0, "slice float4-able");
  static_assert(NSu == 4 || NSu == 8, "butterfly depth");

  const int tid = (int)threadIdx.x;
  const int b   = (int)blockIdx.x;
  const int l   = tid & 63;
  const int wv  = tid >> 6;
  const int sl  = l & (NSu - 1);
  const int u   = wv * UPW + (l / NSu);

  __shared__ __align__(16) float xh0[XH], xh1[XH];

  float w[SL * 4];
  #pragma unroll
  for (int i = 0; i < SL; ++i) {
    const int k = sl * SL + i;
    const float* col = (k < DIN) ? &Wk[(size_t)k * C4H] : &Wr[(size_t)(k - DIN) * C4H];
    #pragma unroll
    for (int g = 0; g < 4; ++g) w[i * 4 + g] = col[g * H + u];
  }
  const float bi_ = bias[u], bf_ = bias[H + u], bg_ = bias[2 * H + u], bo_ = bias[3 * H + u];

  if (tid < H) xh0[DIN + tid] = 0.f;
  if (tid < DIN / 4)
    *((float4*)xh0 + tid) = *(const float4*)&xin[(size_t)b * TT * DIN + 4 * tid];
  BARRIER();

  float cst = 0.f;
  for (int t = 0; t < TT; ++t) {
    float* xc = (t & 1) ? xh1 : xh0;
    float* xn = (t & 1) ? xh0 : xh1;

    float4 xr;
    const bool do_stage = (tid < DIN / 4) && (t + 1 < TT);
    if (do_stage) xr = *(const float4*)&xin[((size_t)b * TT + (t + 1)) * DIN + 4 * tid];

    const float4* xv = (const float4*)(xc + sl * SL);
    float ai = 0.f, af = 0.f, ag = 0.f, ao = 0.f;
    #pragma unroll
    for (int j = 0; j < SL / 4; ++j) {
      const float4 v = xv[j];
      const float* wj = &w[16 * j];
      ai = fmaf(v.x, wj[0],  ai);  af = fmaf(v.x, wj[1],  af);
      ag = fmaf(v.x, wj[2],  ag);  ao = fmaf(v.x, wj[3],  ao);
      ai = fmaf(v.y, wj[4],  ai);  af = fmaf(v.y, wj[5],  af);
      ag = fmaf(v.y, wj[6],  ag);  ao = fmaf(v.y, wj[7],  ao);
      ai = fmaf(v.z, wj[8],  ai);  af = fmaf(v.z, wj[9],  af);
      ag = fmaf(v.z, wj[10], ag);  ao = fmaf(v.z, wj[11], ao);
      ai = fmaf(v.w, wj[12], ai);  af = fmaf(v.w, wj[13], af);
      ag = fmaf(v.w, wj[14], ag);  ao = fmaf(v.w, wj[15], ao);
    }
    ai = dpp_add_xor1(ai); af = dpp_add_xor1(af);
    ag = dpp_add_xor1(ag); ao = dpp_add_xor1(ao);
    ai = dpp_add_xor2(ai); af = dpp_add_xor2(af);
    ag = dpp_add_xor2(ag); ao = dpp_add_xor2(ao);
    if constexpr (NSu == 8) {
      ai = swz_add_xor4(ai); af = swz_add_xor4(af);
      ag = swz_add_xor4(ag); ao = swz_add_xor4(ao);
    }
    const float gi = sigmoid_fast(ai + bi_);
    const float gf = sigmoid_fast(af + bf_);
    const float go = sigmoid_fast(ao + bo_);
    const float gg = fmaxf(ag + bg_, 0.f);
    cst = fmaf(gf, cst, gi * gg);
    const float h = go * fmaxf(cst, 0.f);
    if (sl == 0) {
      xn[DIN + u] = h;
      if constexpr (WRITE_SEQ)  seq_out[((size_t)b * TT + t) * H + u] = h;
      if constexpr (WRITE_LAST) { if (t == TT - 1) last_out[(size_t)b * H + u] = h; }
    }
    if (do_stage) *((float4*)xn + tid) = xr;
    if (t < TT - 1) BARRIER();
  }
}

// ===========================================================================
// dec_fused — r6 VERBATIM (the ~539 us decoder): LSTM3 (const-z fold) +
// gemm3 (coalesced c3=tid streamed Wd2k) + LSTM4 + LDS-read dense pipeline.
// Deliberately NO padding / NO readlane: A/B vs r10's 910 us variant.
// ===========================================================================
__global__ void __launch_bounds__(512, 2)
dec_fused(const float* __restrict__ zrow,  // [B,64]
          const float* __restrict__ Wd1k,  // [64,256]
          const float* __restrict__ Wd1r,  // [64,256]
          const float* __restrict__ bd1,   // [256]
          const float* __restrict__ Wd2k,  // [64,512]
          const float* __restrict__ Wd2r,  // [128,512]
          const float* __restrict__ bd2,   // [512]
          const float* __restrict__ Wout,  // [128,64]
          const float* __restrict__ boutp, // [64]
          float* __restrict__ out)         // [B,T,64]
{
  const int tid = (int)threadIdx.x, b = (int)blockIdx.x;
  const int l  = tid & 63, wv = tid >> 6;
  const int sl1 = l & 3,  u1 = wv * 16 + (l >> 2);   // LSTM4: NSu=4, H=128
  const int sl2 = l & 7,  u2 = wv * 8  + (l >> 3);   // LSTM3: NSu=8, H=64
  const int c3 = tid;                                 // gemm3 column (512)

  __shared__ __align__(16) float zx3[2][8][512];      // d1@Wd2k+bd2
  __shared__ __align__(16) float hd1c[2][8][64];      // d1 h chunks
  __shared__ __align__(16) float hb2d[2][128];        // LSTM4 h ping-pong
  __shared__ __align__(16) float dp[2][512];          // dense partials
  __shared__ __align__(16) float zl[64];

  float w[32];                                        // Wd1r slice
  #pragma unroll
  for (int i = 0; i < 8; ++i) {
    const float* col = Wd1r + (size_t)(sl2 * 8 + i) * 256;
    #pragma unroll
    for (int g = 0; g < 4; ++g) w[i * 4 + g] = col[g * 64 + u2];
  }
  float w1[128];                                      // Wd2r slice
  #pragma unroll
  for (int i = 0; i < 32; ++i) {
    const float* col = Wd2r + (size_t)(sl1 * 32 + i) * 512;
    #pragma unroll
    for (int g = 0; g < 4; ++g) w1[i * 4 + g] = col[g * 128 + u1];
  }
  float wout_r[16];
  #pragma unroll
  for (int jj = 0; jj < 16; ++jj) wout_r[jj] = Wout[(size_t)(16 * wv + jj) * 64 + l];
  const float boutr = boutp[l];
  const float bd2c = bd2[c3];

  if (tid < 16) ((float4*)zl)[tid] = ((const float4*)(zrow + (size_t)b * 64))[tid];
  if (tid < 64)  hd1c[1][7][tid] = 0.f;
  if (tid < 128) hb2d[1][tid]   = 0.f;
  float zxa3[8];
  #pragma unroll
  for (int r = 0; r < 8; ++r) zxa3[r] = bd2c;
  BARRIER();

  // fold z@Wd1k once (per-lane slice partials; bd1 seeded at lane sl2==0)
  float zi = (sl2 == 0) ? bd1[u2]       : 0.f;
  float zf = (sl2 == 0) ? bd1[64 + u2]  : 0.f;
  float zg = (sl2 == 0) ? bd1[128 + u2] : 0.f;
  float zo = (sl2 == 0) ? bd1[192 + u2] : 0.f;
  #pragma unroll
  for (int i = 0; i < 8; ++i) {
    const int k = sl2 * 8 + i;
    const float zv = zl[k];
    const float* col = Wd1k + (size_t)k * 256;
    zi = fmaf(zv, col[u2],       zi);
    zf = fmaf(zv, col[64 + u2],  zf);
    zg = fmaf(zv, col[128 + u2], zg);
    zo = fmaf(zv, col[192 + u2], zo);
  }

  float cst1 = 0.f, cst2 = 0.f;

  for (int t = -8; t < 530; ++t) {
    const int j = t & 7;
    const int ch = t >> 3;
    const bool rd1 = (t >= 0 && t < TT);
    const bool g3  = (t >= 8 && t < 520);             // build chunk ch-1
    const int  s   = t - 16;
    const bool rd2 = (s >= 0 && s < TT);

    float wk3r[8];                                    // coalesced (c3 = tid)
    if (g3) {
      #pragma unroll
      for (int i = 0; i < 8; ++i)
        wk3r[i] = Wd2k[(size_t)(8 * j + i) * 512 + c3];
    }

    // ---- LSTM3 step t (const-z input folded in zi..zo) ----
    if (rd1) {
      const int row = t & 7, buf = ch & 1;
      const int prow = (t - 1) & 7, pbuf = ((t - 1) >> 3) & 1;
      const float4* xv = (const float4*)&hd1c[pbuf][prow][sl2 * 8];
      float ai = zi, af = zf, ag = zg, ao = zo;
      DOT32(xv, w, ai, af, ag, ao);
      ai = dpp_add_xor1(ai); af = dpp_add_xor1(af);
      ag = dpp_add_xor1(ag); ao = dpp_add_xor1(ao);
      ai = dpp_add_xor2(ai); af = dpp_add_xor2(af);
      ag = dpp_add_xor2(ag); ao = dpp_add_xor2(ao);
      ai = swz_add_xor4(ai); af = swz_add_xor4(af);
      ag = swz_add_xor4(ag); ao = swz_add_xor4(ao);
      const float gi = sigmoid_fast(ai);
      const float gf = sigmoid_fast(af);
      const float go = sigmoid_fast(ao);
      const float gg_ = fmaxf(ag, 0.f);
      cst1 = fmaf(gf, cst1, gi * gg_);
      const float h = go * fmaxf(cst1, 0.f);
      if (sl2 == 0) hd1c[buf][row][u2] = h;
    }

    // ---- LSTM4 step s (16 behind) ----
    if (rd2) {
      const int row2 = s & 7, buf2 = (s >> 3) & 1;
      const float4* xv2 = (const float4*)&hb2d[(s + 1) & 1][sl1 * 32];
      const float zq = zx3[buf2][row2][sl1 * 128 + u1];
      float ai = (sl1 == 0) ? zq : 0.f;
      float af = (sl1 == 1) ? zq : 0.f;
      float ag = (sl1 == 2) ? zq : 0.f;
      float ao = (sl1 == 3) ? zq : 0.f;
      DOT128(xv2, w1, ai, af, ag, ao);
      ai = dpp_add_xor1(ai); af = dpp_add_xor1(af);
      ag = dpp_add_xor1(ag); ao = dpp_add_xor1(ao);
      ai = dpp_add_xor2(ai); af = dpp_add_xor2(af);
      ag = dpp_add_xor2(ag); ao = dpp_add_xor2(ao);
      const float gi = sigmoid_fast(ai);
      const float gf = sigmoid_fast(af);
      const float go = sigmoid_fast(ao);
      const float gg_ = fmaxf(ag, 0.f);
      cst2 = fmaf(gf, cst2, gi * gg_);
      const float h2 = go * fmaxf(cst2, 0.f);
      if (sl1 == 0) hb2d[s & 1][u1] = h2;
    }

    // ---- dense partial of h4(s-1); reduce of h4(s-2) ----
    if (s >= 1 && s <= TT) {
      const float4 h0 = *(const float4*)&hb2d[(s + 1) & 1][16 * wv];
      const float4 h1q = *(const float4*)&hb2d[(s + 1) & 1][16 * wv + 4];
      const float4 h2q = *(const float4*)&hb2d[(s + 1) & 1][16 * wv + 8];
      const float4 h3q = *(const float4*)&hb2d[(s + 1) & 1][16 * wv + 12];
      float a = 0.f;
      a = fmaf(h0.x,  wout_r[0],  a);  a = fmaf(h0.y,  wout_r[1],  a);
      a = fmaf(h0.z,  wout_r[2],  a);  a = fmaf(h0.w,  wout_r[3],  a);
      a = fmaf(h1q.x, wout_r[4],  a);  a = fmaf(h1q.y, wout_r[5],  a);
      a = fmaf(h1q.z, wout_r[6],  a);  a = fmaf(h1q.w, wout_r[7],  a);
      a = fmaf(h2q.x, wout_r[8],  a);  a = fmaf(h2q.y, wout_r[9],  a);
      a = fmaf(h2q.z, wout_r[10], a);  a = fmaf(h2q.w, wout_r[11], a);
      a = fmaf(h3q.x, wout_r[12], a);  a = fmaf(h3q.y, wout_r[13], a);
      a = fmaf(h3q.z, wout_r[14], a);  a = fmaf(h3q.w, wout_r[15], a);
      dp[(s - 1) & 1][wv * 64 + l] = a;
    }
    if (s >= 2 && s <= TT + 1 && wv == 7) {
      const float* dq = dp[s & 1];
      float o = boutr;
      #pragma unroll
      for (int q = 0; q < 8; ++q) o += dq[q * 64 + l];
      out[((size_t)b * TT + (s - 2)) * 64 + l] = o;
    }

    // ---- gemm3: zx3 chunk ch-1 from hd1c ----
    if (g3) {
      const int cc = ch - 1;
      #pragma unroll
      for (int r = 0; r < 8; ++r) {
        const float4 ha  = *(const float4*)&hd1c[cc & 1][r][8 * j];
        const float4 hbq = *(const float4*)&hd1c[cc & 1][r][8 * j + 4];
        float a = zxa3[r];
        a = fmaf(ha.x,  wk3r[0], a);  a = fmaf(ha.y,  wk3r[1], a);
        a = fmaf(ha.z,  wk3r[2], a);  a = fmaf(ha.w,  wk3r[3], a);
        a = fmaf(hbq.x, wk3r[4], a);  a = fmaf(hbq.y, wk3r[5], a);
        a = fmaf(hbq.z, wk3r[6], a);  a = fmaf(hbq.w, wk3r[7], a);
        zxa3[r] = a;
      }
      if (j == 7) {
        #pragma unroll
        for (int r = 0; r < 8; ++r) {
          zx3[cc & 1][r][tid] = zxa3[r];
          zxa3[r] = bd2c;
        }
      }
    }

    if (t < 529) BARRIER();
  }
}

extern "C" void kernel_launch(void* const* d_in, const int* in_sizes, int n_in,
                              void* d_out, int out_size, void* d_ws, size_t ws_size,
                              hipStream_t stream) {
  const float* x    = (const float*)d_in[0];
  const float* Wk1  = (const float*)d_in[1];
  const float* Wr1  = (const float*)d_in[2];
  const float* b1   = (const float*)d_in[3];
  const float* Wk2  = (const float*)d_in[4];
  const float* Wr2  = (const float*)d_in[5];
  const float* b2   = (const float*)d_in[6];
  const float* Wd1k = (const float*)d_in[7];
  const float* Wd1r = (const float*)d_in[8];
  const float* bd1  = (const float*)d_in[9];
  const float* Wd2k = (const float*)d_in[10];
  const float* Wd2r = (const float*)d_in[11];
  const float* bd2  = (const float*)d_in[12];
  const float* Wout = (const float*)d_in[13];
  const float* bout = (const float*)d_in[14];
  float* out = (float*)d_out;

  // ws: h1 [B,T,128] (64 MB) + z [B,64] — proven available since r4
  const size_t h1_elems = (size_t)BB * TT * 128;
  if (ws_size < (h1_elems + (size_t)BB * 64) * sizeof(float)) return;
  float* h1 = (float*)d_ws;
  float* z  = h1 + h1_elems;

  // encoder 1: 64 -> 128, seq out (r4-proven, 575 us)
  lstm_unit<64, 128, 4, true,  false><<<BB, 512, 0, stream>>>(x,  Wk1, Wr1, b1, h1, nullptr);
  // encoder 2: 128 -> 64, last state only (r4-proven, ~150 us)
  lstm_unit<128, 64, 8, false, true ><<<BB, 512, 0, stream>>>(h1, Wk2, Wr2, b2, nullptr, z);
  // decoder fused: dec1 + dec2 + Dense — r6 VERBATIM (A/B vs r10's 910 us)
  dec_fused<<<BB, 512, 0, stream>>>(z, Wd1k, Wd1r, bd1, Wd2k, Wd2r, bd2,
                                    Wout, bout, out);
}

// Round 12
// 1415.980 us; speedup vs baseline: 1.0672x; 1.0397x over previous
//
#include <hip/hip_runtime.h>

static constexpr int TT = 512;   // sequence length
static constexpr int BB = 256;   // batch

// LDS-only barrier: no vmcnt(0) drain, so global loads stay in flight across
// it (T4/T14 pattern). lgkmcnt(0) makes prior LDS writes visible.
#define BARRIER() do { \
    asm volatile("s_waitcnt lgkmcnt(0)" ::: "memory"); \
    __builtin_amdgcn_s_barrier(); \
    asm volatile("" ::: "memory"); \
  } while (0)

__device__ __forceinline__ float sigmoid_fast(float v) {
  const float e = __builtin_amdgcn_exp2f(v * -1.44269504088896340736f);
  return __builtin_amdgcn_rcpf(1.0f + e);
}
__device__ __forceinline__ float dpp_add_xor1(float v) {
  const int p = __builtin_amdgcn_update_dpp(0, __builtin_bit_cast(int, v),
                                            0xB1, 0xF, 0xF, true);
  return v + __builtin_bit_cast(float, p);
}
__device__ __forceinline__ float dpp_add_xor2(float v) {
  const int p = __builtin_amdgcn_update_dpp(0, __builtin_bit_cast(int, v),
                                            0x4E, 0xF, 0xF, true);
  return v + __builtin_bit_cast(float, p);
}
__device__ __forceinline__ float swz_add_xor4(float v) {
  const int p = __builtin_amdgcn_ds_swizzle(__builtin_bit_cast(int, v), 0x101F);
  return v + __builtin_bit_cast(float, p);
}

// ============ r4-proven LSTM body (shared by both kernel variants) =========
template<int DIN, int H, int NSu, bool CONST_X, bool WRITE_SEQ, bool WRITE_LAST,
         bool FUSE_DENSE>
__device__ __forceinline__ void lstm_body(
    const float* __restrict__ xin, const float* __restrict__ Wk,
    const float* __restrict__ Wr, const float* __restrict__ bias,
    float* __restrict__ seq_out, float* __restrict__ last_out,
    const float* __restrict__ Wout, const float* __restrict__ boutp,
    float* __restrict__ dense_out)
{
  constexpr int NTH  = 512;
  static_assert(H * NSu == NTH, "block = H*NSu = 512");
  constexpr int KTOT = DIN + H;
  constexpr int SL   = KTOT / NSu;
  constexpr int C4H  = 4 * H;
  constexpr int XH   = DIN + H;
  constexpr int NW   = NTH / 64;
  constexpr int UPW  = 64 / NSu;
  constexpr int DK   = FUSE_DENSE ? (H / NW) : 4;
  static_assert(SL * NSu == KTOT && (SL % 4) == 0, "slice float4-able");
  static_assert(NSu == 4 || NSu == 8, "butterfly depth");

  const int tid = (int)threadIdx.x;
  const int b   = (int)blockIdx.x;
  const int l   = tid & 63;
  const int wv  = tid >> 6;
  const int sl  = l & (NSu - 1);
  const int u   = wv * UPW + (l / NSu);

  __shared__ __align__(16) float xh0[XH], xh1[XH];
  __shared__ __align__(16) float dp[2][FUSE_DENSE ? NW * 64 : 4];

  float w[SL * 4];
  #pragma unroll
  for (int i = 0; i < SL; ++i) {
    const int k = sl * SL + i;
    const float* col = (k < DIN) ? &Wk[(size_t)k * C4H] : &Wr[(size_t)(k - DIN) * C4H];
    #pragma unroll
    for (int g = 0; g < 4; ++g) w[i * 4 + g] = col[g * H + u];
  }
  const float bi_ = bias[u], bf_ = bias[H + u], bg_ = bias[2 * H + u], bo_ = bias[3 * H + u];

  float wout_r[DK];
  float boutr = 0.f;
  if constexpr (FUSE_DENSE) {
    #pragma unroll
    for (int j = 0; j < DK; ++j) wout_r[j] = Wout[(size_t)(DK * wv + j) * 64 + l];
    boutr = boutp[l];
  }

  if (tid < H) xh0[DIN + tid] = 0.f;
  if (tid < DIN / 4) {
    const float4 v = *(const float4*)&xin[(CONST_X ? (size_t)b * DIN
                                                   : (size_t)b * TT * DIN) + 4 * tid];
    *((float4*)xh0 + tid) = v;
    if (CONST_X) *((float4*)xh1 + tid) = v;
  }
  BARRIER();

  float cst = 0.f;
  constexpr int TEND = FUSE_DENSE ? TT + 2 : TT;

  for (int t = 0; t < TEND; ++t) {
    float* xc = (t & 1) ? xh1 : xh0;
    float* xn = (t & 1) ? xh0 : xh1;

    float4 xr;
    const bool do_stage = (!CONST_X) && (tid < DIN / 4) && (t + 1 < TT);
    if (do_stage) xr = *(const float4*)&xin[((size_t)b * TT + (t + 1)) * DIN + 4 * tid];

    if (t < TT) {
      const float4* xv = (const float4*)(xc + sl * SL);
      float ai = 0.f, af = 0.f, ag = 0.f, ao = 0.f;
      #pragma unroll
      for (int j = 0; j < SL / 4; ++j) {
        const float4 v = xv[j];
        const float* wj = &w[16 * j];
        ai = fmaf(v.x, wj[0],  ai);  af = fmaf(v.x, wj[1],  af);
        ag = fmaf(v.x, wj[2],  ag);  ao = fmaf(v.x, wj[3],  ao);
        ai = fmaf(v.y, wj[4],  ai);  af = fmaf(v.y, wj[5],  af);
        ag = fmaf(v.y, wj[6],  ag);  ao = fmaf(v.y, wj[7],  ao);
        ai = fmaf(v.z, wj[8],  ai);  af = fmaf(v.z, wj[9],  af);
        ag = fmaf(v.z, wj[10], ag);  ao = fmaf(v.z, wj[11], ao);
        ai = fmaf(v.w, wj[12], ai);  af = fmaf(v.w, wj[13], af);
        ag = fmaf(v.w, wj[14], ag);  ao = fmaf(v.w, wj[15], ao);
      }
      ai = dpp_add_xor1(ai); af = dpp_add_xor1(af);
      ag = dpp_add_xor1(ag); ao = dpp_add_xor1(ao);
      ai = dpp_add_xor2(ai); af = dpp_add_xor2(af);
      ag = dpp_add_xor2(ag); ao = dpp_add_xor2(ao);
      if constexpr (NSu == 8) {
        ai = swz_add_xor4(ai); af = swz_add_xor4(af);
        ag = swz_add_xor4(ag); ao = swz_add_xor4(ao);
      }
      const float gi = sigmoid_fast(ai + bi_);
      const float gf = sigmoid_fast(af + bf_);
      const float go = sigmoid_fast(ao + bo_);
      const float gg = fmaxf(ag + bg_, 0.f);       // activation = relu
      cst = fmaf(gf, cst, gi * gg);                // c = f*c + i*g
      const float h = go * fmaxf(cst, 0.f);        // h = o * relu(c)
      if (sl == 0) {
        xn[DIN + u] = h;
        if constexpr (WRITE_SEQ)  seq_out[((size_t)b * TT + t) * H + u] = h;
        if constexpr (WRITE_LAST) { if (t == TT - 1) last_out[(size_t)b * H + u] = h; }
      }
    }
    if (do_stage) *((float4*)xn + tid) = xr;

    if constexpr (FUSE_DENSE) {
      if (t >= 1 && t <= TT) {
        const float* hsrc = xc + DIN + DK * wv;
        float a = 0.f;
        #pragma unroll
        for (int j = 0; j < DK; j += 4) {
          const float4 hv = *(const float4*)(hsrc + j);
          a = fmaf(hv.x, wout_r[j + 0], a);
          a = fmaf(hv.y, wout_r[j + 1], a);
          a = fmaf(hv.z, wout_r[j + 2], a);
          a = fmaf(hv.w, wout_r[j + 3], a);
        }
        dp[(t - 1) & 1][wv * 64 + l] = a;
      }
      if (t >= 2 && wv == NW - 1) {
        const float* dq = dp[t & 1];
        float o = boutr;
        #pragma unroll
        for (int j = 0; j < NW; ++j) o += dq[j * 64 + l];
        dense_out[((size_t)b * TT + (t - 2)) * 64 + l] = o;
      }
    }
    if (t < TEND - 1) BARRIER();
  }
}

// Control variant: r4's exact launch config (128 arch VGPR + AGPR split)
template<int DIN, int H, int NSu, bool CONST_X, bool WRITE_SEQ, bool WRITE_LAST,
         bool FUSE_DENSE>
__global__ void __launch_bounds__(512, 2)
lstm_unit(const float* __restrict__ xin, const float* __restrict__ Wk,
          const float* __restrict__ Wr, const float* __restrict__ bias,
          float* __restrict__ seq_out, float* __restrict__ last_out,
          const float* __restrict__ Wout, const float* __restrict__ boutp,
          float* __restrict__ dense_out)
{
  lstm_body<DIN, H, NSu, CONST_X, WRITE_SEQ, WRITE_LAST, FUSE_DENSE>(
      xin, Wk, Wr, bias, seq_out, last_out, Wout, boutp, dense_out);
}

// Test variant: request 256 arch VGPRs (full 512-reg file at 2 waves/SIMD)
// so w[192] can be architectural -> no AGPR round-trip in the hot loop.
template<int DIN, int H, int NSu, bool CONST_X, bool WRITE_SEQ, bool WRITE_LAST,
         bool FUSE_DENSE>
__global__ void __launch_bounds__(512)
__attribute__((amdgpu_num_vgpr(256)))
lstm_unit_v256(const float* __restrict__ xin, const float* __restrict__ Wk,
               const float* __restrict__ Wr, const float* __restrict__ bias,
               float* __restrict__ seq_out, float* __restrict__ last_out,
               const float* __restrict__ Wout, const float* __restrict__ boutp,
               float* __restrict__ dense_out)
{
  lstm_body<DIN, H, NSu, CONST_X, WRITE_SEQ, WRITE_LAST, FUSE_DENSE>(
      xin, Wk, Wr, bias, seq_out, last_out, Wout, boutp, dense_out);
}

extern "C" void kernel_launch(void* const* d_in, const int* in_sizes, int n_in,
                              void* d_out, int out_size, void* d_ws, size_t ws_size,
                              hipStream_t stream) {
  const float* x    = (const float*)d_in[0];
  const float* Wk1  = (const float*)d_in[1];
  const float* Wr1  = (const float*)d_in[2];
  const float* b1   = (const float*)d_in[3];
  const float* Wk2  = (const float*)d_in[4];
  const float* Wr2  = (const float*)d_in[5];
  const float* b2   = (const float*)d_in[6];
  const float* Wd1k = (const float*)d_in[7];
  const float* Wd1r = (const float*)d_in[8];
  const float* bd1  = (const float*)d_in[9];
  const float* Wd2k = (const float*)d_in[10];
  const float* Wd2r = (const float*)d_in[11];
  const float* bd2  = (const float*)d_in[12];
  const float* Wout = (const float*)d_in[13];
  const float* bout = (const float*)d_in[14];
  float* out = (float*)d_out;

  // ws: h1 [B,T,128] (64 MB; d1 [B,T,64] overlays it after enc2), z [B,64]
  const size_t h1_elems = (size_t)BB * TT * 128;
  if (ws_size < (h1_elems + (size_t)BB * 64) * sizeof(float)) return;
  float* h1 = (float*)d_ws;
  float* z  = h1 + h1_elems;
  float* d1 = h1;  // h1 dead after enc2

  // encoder 1 (TEST: amdgpu_num_vgpr(256)): 64 -> 128, seq out
  lstm_unit_v256<64, 128, 4, false, true,  false, false><<<BB, 512, 0, stream>>>(
      x,  Wk1,  Wr1,  b1,  h1,      nullptr, nullptr, nullptr, nullptr);
  // encoder 2 (control): 128 -> 64, last state only
  lstm_unit<128, 64, 8, false, false, true,  false><<<BB, 512, 0, stream>>>(
      h1, Wk2,  Wr2,  b2,  nullptr, z,       nullptr, nullptr, nullptr);
  // decoder 1 (control): const z (RepeatVector) -> 64
  lstm_unit<64,  64, 8, true,  true,  false, false><<<BB, 512, 0, stream>>>(
      z,  Wd1k, Wd1r, bd1, d1,      nullptr, nullptr, nullptr, nullptr);
  // decoder 2 (CONTROL for the A/B, same workload class as enc1):
  // 64 -> 128 + fused Dense 128->64
  lstm_unit<64, 128, 4, false, false, false, true ><<<BB, 512, 0, stream>>>(
      d1, Wd2k, Wd2r, bd2, nullptr, nullptr, Wout,   bout,    out);
}